// Round 1
// baseline (1103.389 us; speedup 1.0000x reference)
//
#include <hip/hip_runtime.h>

#define GRIDS 8400
#define TNB   256
#define NCV   80
#define TOPKV 13
#define EPSF  1e-9f

__global__ __launch_bounds__(256) void taa_kernel(
    const float* __restrict__ pd_scores,
    const float* __restrict__ pd_bboxes,
    const float* __restrict__ anc,
    const int*   __restrict__ gt_labels,
    const float* __restrict__ gt_bboxes,
    float* __restrict__ out_labels,
    float* __restrict__ out_bboxes,
    float* __restrict__ out_scores,
    float* __restrict__ out_mask)
{
    __shared__ float smet[GRIDS];
    __shared__ float rv[256];
    __shared__ int   ri[256];
    __shared__ int   sel_idx[TOPKV];
    __shared__ float sel_val[TOPKV];
    __shared__ float sel_am[TOPKV];
    __shared__ float sel_ov[TOPKV];
    __shared__ int   sel_in[TOPKV];

    const int t   = blockIdx.x;
    const int tid = threadIdx.x;

    const float gx1 = gt_bboxes[t*4+0];
    const float gy1 = gt_bboxes[t*4+1];
    const float gx2 = gt_bboxes[t*4+2];
    const float gy2 = gt_bboxes[t*4+3];
    const int   lab = gt_labels[t];
    const float garea = fmaxf(gx2-gx1, 0.f) * fmaxf(gy2-gy1, 0.f);

    const float4* pb = reinterpret_cast<const float4*>(pd_bboxes) + (size_t)t*GRIDS;
    const float*  ps = pd_scores + (size_t)t*GRIDS*NCV + lab;

    // Phase 0: fused zero-fill of this row's output slices (replaces the
    // device-wide memset, which was 4x oversized: out_size is BYTES, the old
    // launch memset out_size*4 = 2.96 GB = ~480 us/iter at 6.1 TB/s).
    // Block t exclusively owns row t of every output, so this is race-free;
    // the <=13 scatter overwrites happen after later __syncthreads() (vmcnt
    // drained), so ordering vs these zero stores is guaranteed.
    {
        const float4 z4 = make_float4(0.f, 0.f, 0.f, 0.f);
        float4* zs = reinterpret_cast<float4*>(out_scores + (size_t)t*GRIDS*NCV);
        for (int i = tid; i < GRIDS*NCV/4; i += 256) zs[i] = z4;     // 168000 float4
        float4* zb = reinterpret_cast<float4*>(out_bboxes + (size_t)t*GRIDS*4);
        for (int i = tid; i < GRIDS; i += 256) zb[i] = z4;           // 8400 float4
        float4* zl = reinterpret_cast<float4*>(out_labels + (size_t)t*GRIDS);
        float4* zm = reinterpret_cast<float4*>(out_mask   + (size_t)t*GRIDS);
        for (int i = tid; i < GRIDS/4; i += 256) { zl[i] = z4; zm[i] = z4; } // 2100 each
    }

    // Pass 1: masked align metric into LDS
    for (int g = tid; g < GRIDS; g += 256) {
        float ax = anc[2*g], ay = anc[2*g+1];
        float dmin = fminf(fminf(ax-gx1, ay-gy1), fminf(gx2-ax, gy2-ay));
        float4 p = pb[g];
        float ix1 = fmaxf(gx1, p.x), iy1 = fmaxf(gy1, p.y);
        float ix2 = fminf(gx2, p.z), iy2 = fminf(gy2, p.w);
        float ov  = fmaxf(ix2-ix1, 0.f) * fmaxf(iy2-iy1, 0.f);
        float pa  = fmaxf(p.z-p.x, 0.f) * fmaxf(p.w-p.y, 0.f);
        float iou = ov / (garea + pa - ov + EPSF);
        float sc  = ps[(size_t)g*NCV];
        float i2  = iou*iou;
        float m   = sc * (i2*i2*i2);
        smet[g] = (dmin > EPSF) ? m : 0.f;
    }
    __syncthreads();

    // Top-13: iterated stable argmax (tie -> lowest index), knock out with -1
    for (int k = 0; k < TOPKV; ++k) {
        float bv = -1.f; int bi = GRIDS;
        for (int g = tid; g < GRIDS; g += 256) {
            float v = smet[g];
            if (v > bv) { bv = v; bi = g; }   // within-thread g increases: first-equal wins
        }
        rv[tid] = bv; ri[tid] = bi;
        __syncthreads();
        for (int s = 128; s > 0; s >>= 1) {
            if (tid < s) {
                float v2 = rv[tid+s]; int j2 = ri[tid+s];
                if (v2 > rv[tid] || (v2 == rv[tid] && j2 < ri[tid])) { rv[tid] = v2; ri[tid] = j2; }
            }
            __syncthreads();
        }
        if (tid == 0) {
            int gi = ri[0];
            sel_idx[k] = gi;
            sel_val[k] = rv[0];
            smet[gi] = -1.f;
        }
        __syncthreads();
    }

    // Tail: recompute in_gts / iou at the 13 selected anchors
    if (tid < TOPKV) {
        int g = sel_idx[tid];
        float ax = anc[2*g], ay = anc[2*g+1];
        float dmin = fminf(fminf(ax-gx1, ay-gy1), fminf(gx2-ax, gy2-ay));
        bool ing = dmin > EPSF;
        float4 p = pb[g];
        float ix1 = fmaxf(gx1, p.x), iy1 = fmaxf(gy1, p.y);
        float ix2 = fminf(gx2, p.z), iy2 = fminf(gy2, p.w);
        float ov  = fmaxf(ix2-ix1, 0.f) * fmaxf(iy2-iy1, 0.f);
        float pa  = fmaxf(p.z-p.x, 0.f) * fmaxf(p.w-p.y, 0.f);
        float iou = ov / (garea + pa - ov + EPSF);
        sel_in[tid] = ing ? 1 : 0;
        sel_am[tid] = ing ? sel_val[tid] : 0.f;  // am = align * mask_pos
        sel_ov[tid] = ing ? iou : 0.f;           // overlaps * mask_pos
    }
    __syncthreads();

    // Scatter outputs at mask_pos positions
    if (tid < TOPKV && sel_in[tid]) {
        float pa = 0.f, po = 0.f;
        for (int k = 0; k < TOPKV; ++k) {
            pa = fmaxf(pa, sel_am[k]);
            po = fmaxf(po, sel_ov[k]);
        }
        float norm = sel_am[tid] * po / (pa + EPSF);
        int g = sel_idx[tid];
        size_t off = (size_t)t*GRIDS + g;
        out_labels[off] = (float)lab;
        out_mask[off]   = 1.0f;
        float4 gb; gb.x = gx1; gb.y = gy1; gb.z = gx2; gb.w = gy2;
        reinterpret_cast<float4*>(out_bboxes)[off] = gb;
        out_scores[off*(size_t)NCV + lab] = norm;
    }
}

extern "C" void kernel_launch(void* const* d_in, const int* in_sizes, int n_in,
                              void* d_out, int out_size, void* d_ws, size_t ws_size,
                              hipStream_t stream)
{
    const float* pd_scores = (const float*)d_in[0];
    const float* pd_bboxes = (const float*)d_in[1];
    const float* anc       = (const float*)d_in[2];
    const int*   gt_labels = (const int*)d_in[3];
    const float* gt_bboxes = (const float*)d_in[4];
    float* out = (float*)d_out;

    float* out_labels = out;
    float* out_bboxes = out_labels + (size_t)TNB*GRIDS;
    float* out_scores = out_bboxes + (size_t)TNB*GRIDS*4;
    float* out_mask   = out_scores + (size_t)TNB*GRIDS*NCV;

    // No memset: each block zero-fills its own output row inside the kernel.
    taa_kernel<<<TNB, 256, 0, stream>>>(pd_scores, pd_bboxes, anc, gt_labels, gt_bboxes,
                                        out_labels, out_bboxes, out_scores, out_mask);
}

// Round 2
// 1081.362 us; speedup vs baseline: 1.0204x; 1.0204x over previous
//
#include <hip/hip_runtime.h>

#define GRIDS 8400
#define TNB   256
#define NCV   80
#define TOPKV 13
#define EPSF  1e-9f

__global__ __launch_bounds__(256) void taa_kernel(
    const float* __restrict__ pd_scores,
    const float* __restrict__ pd_bboxes,
    const float* __restrict__ anc,
    const int*   __restrict__ gt_labels,
    const float* __restrict__ gt_bboxes,
    float* __restrict__ out_labels,
    float* __restrict__ out_bboxes,
    float* __restrict__ out_scores,
    float* __restrict__ out_mask)
{
    __shared__ float smet[GRIDS];
    __shared__ float rv[256];
    __shared__ int   ri[256];
    __shared__ int   sel_idx[TOPKV];
    __shared__ float sel_val[TOPKV];
    __shared__ float sel_am[TOPKV];
    __shared__ float sel_ov[TOPKV];
    __shared__ int   sel_in[TOPKV];

    const int t   = blockIdx.x;
    const int tid = threadIdx.x;

    const float gx1 = gt_bboxes[t*4+0];
    const float gy1 = gt_bboxes[t*4+1];
    const float gx2 = gt_bboxes[t*4+2];
    const float gy2 = gt_bboxes[t*4+3];
    const int   lab = gt_labels[t];
    const float garea = fmaxf(gx2-gx1, 0.f) * fmaxf(gy2-gy1, 0.f);

    const float4* pb = reinterpret_cast<const float4*>(pd_bboxes) + (size_t)t*GRIDS;
    const float*  ps = pd_scores + (size_t)t*GRIDS*NCV + lab;

    // Pass 1: masked align metric into LDS
    for (int g = tid; g < GRIDS; g += 256) {
        float ax = anc[2*g], ay = anc[2*g+1];
        float dmin = fminf(fminf(ax-gx1, ay-gy1), fminf(gx2-ax, gy2-ay));
        float4 p = pb[g];
        float ix1 = fmaxf(gx1, p.x), iy1 = fmaxf(gy1, p.y);
        float ix2 = fminf(gx2, p.z), iy2 = fminf(gy2, p.w);
        float ov  = fmaxf(ix2-ix1, 0.f) * fmaxf(iy2-iy1, 0.f);
        float pa  = fmaxf(p.z-p.x, 0.f) * fmaxf(p.w-p.y, 0.f);
        float iou = ov / (garea + pa - ov + EPSF);
        float sc  = ps[(size_t)g*NCV];
        float i2  = iou*iou;
        float m   = sc * (i2*i2*i2);
        smet[g] = (dmin > EPSF) ? m : 0.f;
    }
    __syncthreads();

    // Top-13: iterated stable argmax (tie -> lowest index), knock out with -1
    for (int k = 0; k < TOPKV; ++k) {
        float bv = -1.f; int bi = GRIDS;
        for (int g = tid; g < GRIDS; g += 256) {
            float v = smet[g];
            if (v > bv) { bv = v; bi = g; }   // within-thread g increases: first-equal wins
        }
        rv[tid] = bv; ri[tid] = bi;
        __syncthreads();
        for (int s = 128; s > 0; s >>= 1) {
            if (tid < s) {
                float v2 = rv[tid+s]; int j2 = ri[tid+s];
                if (v2 > rv[tid] || (v2 == rv[tid] && j2 < ri[tid])) { rv[tid] = v2; ri[tid] = j2; }
            }
            __syncthreads();
        }
        if (tid == 0) {
            int gi = ri[0];
            sel_idx[k] = gi;
            sel_val[k] = rv[0];
            smet[gi] = -1.f;
        }
        __syncthreads();
    }

    // Tail: recompute in_gts / iou at the 13 selected anchors
    if (tid < TOPKV) {
        int g = sel_idx[tid];
        float ax = anc[2*g], ay = anc[2*g+1];
        float dmin = fminf(fminf(ax-gx1, ay-gy1), fminf(gx2-ax, gy2-ay));
        bool ing = dmin > EPSF;
        float4 p = pb[g];
        float ix1 = fmaxf(gx1, p.x), iy1 = fmaxf(gy1, p.y);
        float ix2 = fminf(gx2, p.z), iy2 = fminf(gy2, p.w);
        float ov  = fmaxf(ix2-ix1, 0.f) * fmaxf(iy2-iy1, 0.f);
        float pa  = fmaxf(p.z-p.x, 0.f) * fmaxf(p.w-p.y, 0.f);
        float iou = ov / (garea + pa - ov + EPSF);
        sel_in[tid] = ing ? 1 : 0;
        sel_am[tid] = ing ? sel_val[tid] : 0.f;  // am = align * mask_pos
        sel_ov[tid] = ing ? iou : 0.f;           // overlaps * mask_pos
    }
    __syncthreads();

    // Scatter outputs at mask_pos positions
    if (tid < TOPKV && sel_in[tid]) {
        float pa = 0.f, po = 0.f;
        for (int k = 0; k < TOPKV; ++k) {
            pa = fmaxf(pa, sel_am[k]);
            po = fmaxf(po, sel_ov[k]);
        }
        float norm = sel_am[tid] * po / (pa + EPSF);
        int g = sel_idx[tid];
        size_t off = (size_t)t*GRIDS + g;
        out_labels[off] = (float)lab;
        out_mask[off]   = 1.0f;
        float4 gb; gb.x = gx1; gb.y = gy1; gb.z = gx2; gb.w = gy2;
        reinterpret_cast<float4*>(out_bboxes)[off] = gb;
        out_scores[off*(size_t)NCV + lab] = norm;
    }
}

extern "C" void kernel_launch(void* const* d_in, const int* in_sizes, int n_in,
                              void* d_out, int out_size, void* d_ws, size_t ws_size,
                              hipStream_t stream)
{
    const float* pd_scores = (const float*)d_in[0];
    const float* pd_bboxes = (const float*)d_in[1];
    const float* anc       = (const float*)d_in[2];
    const int*   gt_labels = (const int*)d_in[3];
    const float* gt_bboxes = (const float*)d_in[4];
    float* out = (float*)d_out;

    // Outputs are ~0 everywhere except <=13 positions per row: zero-fill then scatter.
    // (Measured A/B round0 vs round1: the rocclr fill at large grid sustains
    // ~6.26 TB/s; fusing this 739.7 MB zero into the 256-block compute kernel
    // fills at only ~5.6 TB/s — memset + light kernel is the faster split.)
    hipMemsetAsync(d_out, 0, (size_t)out_size * sizeof(float), stream);

    float* out_labels = out;
    float* out_bboxes = out_labels + (size_t)TNB*GRIDS;
    float* out_scores = out_bboxes + (size_t)TNB*GRIDS*4;
    float* out_mask   = out_scores + (size_t)TNB*GRIDS*NCV;

    taa_kernel<<<TNB, 256, 0, stream>>>(pd_scores, pd_bboxes, anc, gt_labels, gt_bboxes,
                                        out_labels, out_bboxes, out_scores, out_mask);
}